// Round 9
// baseline (266.370 us; speedup 1.0000x reference)
//
// ============================================================================
// Round 22: spmm concurrency fix. BUCKET 64->32 (NB 782->1563), 512-thr
// blocks: 64 groups = 32 nodes x 2 parity-halves; pair-combine via ONE
// __shfl_xor(acc,8) (partners in same wave -- no LDS/barrier/atomic). Grid
// 1563x8 waves = 12.5K waves -> saturates the 32-wave/CU cap (was 24.4) and
// halves block lifetime -> tail halves. Partition/count/off move to 5-bit
// bins (dst>>5, (dst&31)<<16); pg scan 4 segments (+~2us). Loads stay 16B.
// Everything else IDENTICAL to R21.
//
// Measured R21: 257.6 (3rd neutral round; work-deletion no longer moves
// total). spmm 73.1: VALU 31%, FETCH 148MB = 2.0TB/s L2-miss -> latency-
// bound, grid-starved at 24.4/32 waves/CU.
//
// Predicted: spmm -> 55-62 (Occ up, FETCH/WRITE unchanged, conflicts may
// rise to 1.5-2.5M), pg +1-3, total -> ~240-248. absmax 0.001953125 (parity
// interleave = fp32 order only). Pre-commit: spmm >= 68 -> gather is
// L2-miss-BW-bound -> declare ROOFLINE next round.
// ============================================================================
#include <hip/hip_runtime.h>

#define KDIM 128
#define NCOLS 64
// u8-packed src-degree histogram: one range, 50000 bins / 4 per word
#define NHCH 64
#define HW 12500
// fine buckets (partition + spmm granularity)
#define BUCKET 32
#define NB5 1563
#define FCAP 1408
// partition blocks per graph
#define NPB 85
// prep task ranges
#define PREP_HIST (3 * NHCH)   // 192 hist blocks
#define PREP_CNT  (3 * NPB)    // 255 bucket-count blocks
#define PREP_WF   12           // wfrag blocks
#define PREP_GRID (PREP_HIST + PREP_CNT + PREP_WF)   // 459
// pg (partition + gemm fused): partition FIRST (long pole)
#define PG_PART (3 * NPB)            // 255
#define PG_GEMM_PER 391              // (50000+127)/128
#define PG_GEMM (3 * PG_GEMM_PER)    // 1173
#define PG_GRID (PG_PART + PG_GEMM)  // 1428

typedef __attribute__((ext_vector_type(8))) short bf16x8;
typedef __attribute__((ext_vector_type(4))) float f32x4;

struct GArgs {
  const int*   src[3];
  const int*   dst[3];
  const float* W[3];
  const float* b[3];
  int          E[3];
};

__device__ __forceinline__ unsigned short f2bf(float f) {
  unsigned u = __float_as_uint(f);
  u += 0x7FFFu + ((u >> 16) & 1u);   // RNE
  return (unsigned short)(u >> 16);
}
__device__ __forceinline__ float bflo(unsigned u) { return __uint_as_float(u << 16); }
__device__ __forceinline__ float bfhi(unsigned u) { return __uint_as_float(u & 0xFFFF0000u); }

// load 8 fp32 -> bf16x8 fragment (RNE, bit-identical to staged conversion)
__device__ __forceinline__ bf16x8 ld_cvt8(const float* __restrict__ p) {
  float4 f0 = *(const float4*)p;
  float4 f1 = *(const float4*)(p + 4);
  union { uint4 u; bf16x8 v; } cv;
  cv.u.x = (unsigned)f2bf(f0.x) | ((unsigned)f2bf(f0.y) << 16);
  cv.u.y = (unsigned)f2bf(f0.z) | ((unsigned)f2bf(f0.w) << 16);
  cv.u.z = (unsigned)f2bf(f1.x) | ((unsigned)f2bf(f1.y) << 16);
  cv.u.w = (unsigned)f2bf(f1.z) | ((unsigned)f2bf(f1.w) << 16);
  return cv.v;
}

// ---------------- fused front-end: hist | count(+Pcnt) | wfrag --------------
__global__ __launch_bounds__(256) void prep_kernel(
    GArgs A, unsigned short* __restrict__ Wf, unsigned* __restrict__ P8,
    int* __restrict__ tot, int* __restrict__ Pcnt) {
  __shared__ unsigned sbuf[HW];   // 50 KB; hist uses all, count uses prefix
  const int b = blockIdx.x;
  const int t = threadIdx.x;

  if (b < PREP_HIST) {
    // -------- u8-packed src histogram, single pass over all 50000 bins -----
    const int g = b >> 6;
    const int chunk = b & 63;
    const int E = A.E[g];
    const int per_chunk = (((E + NHCH - 1) / NHCH) + 3) & ~3;
    const int* __restrict__ keys = A.src[g];
    for (int i = t; i < HW; i += 256) sbuf[i] = 0;
    __syncthreads();
    const int e0 = chunk * per_chunk;
    const int e1 = min(e0 + per_chunk, E);
    const int nn = max(e1 - e0, 0);
    const int nv = nn >> 2;
    const int4* k4p = (const int4*)&keys[e0];
    for (int v = t; v < nv; v += 256) {
      int4 k = k4p[v];
      atomicAdd(&sbuf[(unsigned)k.x >> 2], 1u << (((unsigned)k.x & 3u) * 8));
      atomicAdd(&sbuf[(unsigned)k.y >> 2], 1u << (((unsigned)k.y & 3u) * 8));
      atomicAdd(&sbuf[(unsigned)k.z >> 2], 1u << (((unsigned)k.z & 3u) * 8));
      atomicAdd(&sbuf[(unsigned)k.w >> 2], 1u << (((unsigned)k.w & 3u) * 8));
    }
    for (int e = e0 + (nv << 2) + t; e < e1; e += 256) {
      unsigned k = (unsigned)keys[e];
      atomicAdd(&sbuf[k >> 2], 1u << ((k & 3u) * 8));
    }
    __syncthreads();
    unsigned* __restrict__ dstp = P8 + (size_t)b * HW;   // b == g*64+chunk
    for (int i = t; i < HW; i += 256) dstp[i] = sbuf[i];

  } else if (b < PREP_HIST + PREP_CNT) {
    // -------- fine bucket (dst>>5) count; persist per-block counts ---------
    const int bb = b - PREP_HIST;
    const int g = bb / NPB;
    const int blk = bb % NPB;
    const int E = A.E[g];
    const int per_block = (((E + NPB - 1) / NPB) + 3) & ~3;
    const int* __restrict__ dst = A.dst[g];
    int* hcnt = (int*)sbuf;
    for (int i = t; i < NB5; i += 256) hcnt[i] = 0;
    __syncthreads();
    const int e0 = blk * per_block;
    const int e1 = min(e0 + per_block, E);
    const int nn = max(e1 - e0, 0);
    const int nv = nn >> 2;
    const int4* d4 = (const int4*)&dst[e0];
    for (int v = t; v < nv; v += 256) {
      int4 d = d4[v];
      atomicAdd(&hcnt[(unsigned)d.x >> 5], 1);
      atomicAdd(&hcnt[(unsigned)d.y >> 5], 1);
      atomicAdd(&hcnt[(unsigned)d.z >> 5], 1);
      atomicAdd(&hcnt[(unsigned)d.w >> 5], 1);
    }
    for (int e = e0 + (nv << 2) + t; e < e1; e += 256)
      atomicAdd(&hcnt[(unsigned)dst[e] >> 5], 1);
    __syncthreads();
    int* __restrict__ pc = Pcnt + (size_t)bb * NB5;
    for (int i = t; i < NB5; i += 256) {
      int c = hcnt[i];
      pc[i] = c;
      if (c) atomicAdd(&tot[g * NB5 + i], c);
    }

  } else {
    // -------- W -> MFMA B-fragment layout, PERMUTED columns ----------------
    // B-frag (c, lane n) holds logical W column (4n + c): MFMA C/D at lane n,
    // acc[c][r] is logical col 4n+c -> contiguous 8B epilogue store.
    int tid = (b - PREP_HIST - PREP_CNT) * 256 + t;   // < 3072 always
    int lane = tid & 63;
    int frag = (tid >> 6) & 15;
    int g = tid >> 10;
    int c = frag >> 2, kk = frag & 3;
    int n = lane & 15, quad = lane >> 4;
    const float* W = A.W[g];
    unsigned short v[8];
    #pragma unroll
    for (int j = 0; j < 8; ++j) {
      int k = 32 * kk + quad * 8 + j;
      v[j] = f2bf(W[k * 64 + 4 * n + c]);
    }
    uint4 u;
    u.x = (unsigned)v[0] | ((unsigned)v[1] << 16);
    u.y = (unsigned)v[2] | ((unsigned)v[3] << 16);
    u.z = (unsigned)v[4] | ((unsigned)v[5] << 16);
    u.w = (unsigned)v[6] | ((unsigned)v[7] << 16);
    ((uint4*)Wf)[tid] = u;
  }
}

// ---------------- fused partition + MFMA GEMM -------------------------------
__global__ __launch_bounds__(512) void pg_kernel(
    GArgs A, const float* __restrict__ h,
    const unsigned short* __restrict__ Wf, const unsigned* __restrict__ P8,
    const int* __restrict__ tot, const int* __restrict__ Pcnt,
    int* __restrict__ cursor, int* __restrict__ off, unsigned* __restrict__ P2,
    unsigned short* __restrict__ x, int N, int Emax) {
  __shared__ int lcnt[NB5];
  __shared__ int lcur[NB5];
  __shared__ int sd[512];
  const int b = blockIdx.x;
  const int t = threadIdx.x;

  if (b < PG_PART) {
    // ---------------- fine partition: load Pcnt, scan, scatter (1 pass) ----
    const int g = b / NPB;
    const int blk = b % NPB;
    const int E = A.E[g];
    const int per_block = (((E + NPB - 1) / NPB) + 3) & ~3;
    const int* __restrict__ src = A.src[g];
    const int* __restrict__ dst = A.dst[g];
    unsigned* __restrict__ P2g = P2 + (size_t)g * Emax;

    const int* __restrict__ pc = Pcnt + (size_t)b * NB5;
    for (int i = t; i < NB5; i += 512) lcnt[i] = pc[i];

    // redundant exclusive scan of tot[g] over 1563 bins
    int base = 0;
    for (int c0 = 0; c0 < NB5; c0 += 512) {
      int idx = c0 + t;
      int v = (idx < NB5) ? tot[g * NB5 + idx] : 0;
      sd[t] = v;
      __syncthreads();
      for (int o = 1; o < 512; o <<= 1) {
        int add = (t >= o) ? sd[t - o] : 0;
        __syncthreads();
        sd[t] += add;
        __syncthreads();
      }
      int excl = base + sd[t] - v;
      if (idx < NB5) {
        lcur[idx] = excl;
        if (blk == 0) off[g * (NB5 + 1) + idx] = excl;
      }
      base += sd[511];
      __syncthreads();
    }
    if (blk == 0 && t == 0) off[g * (NB5 + 1) + NB5] = base;

    // reserve this block's region per bin
    for (int i = t; i < NB5; i += 512) {
      int c = lcnt[i];
      if (c) lcur[i] += atomicAdd(&cursor[g * NB5 + i], c);
    }
    __syncthreads();

    const int e0 = blk * per_block;
    const int e1 = min(e0 + per_block, E);
    const int nn = max(e1 - e0, 0);
    const int nv = nn >> 2;
    const int4* d4 = (const int4*)&dst[e0];
    const int4* s4 = (const int4*)&src[e0];
    for (int v = t; v < nv; v += 512) {
      int4 d = d4[v];
      int4 s = s4[v];
      unsigned bk; int pos;
      bk = (unsigned)d.x >> 5; pos = atomicAdd(&lcur[bk], 1);
      P2g[pos] = (unsigned)s.x | (((unsigned)d.x & 31u) << 16);
      bk = (unsigned)d.y >> 5; pos = atomicAdd(&lcur[bk], 1);
      P2g[pos] = (unsigned)s.y | (((unsigned)d.y & 31u) << 16);
      bk = (unsigned)d.z >> 5; pos = atomicAdd(&lcur[bk], 1);
      P2g[pos] = (unsigned)s.z | (((unsigned)d.z & 31u) << 16);
      bk = (unsigned)d.w >> 5; pos = atomicAdd(&lcur[bk], 1);
      P2g[pos] = (unsigned)s.w | (((unsigned)d.w & 31u) << 16);
    }
    for (int e = e0 + (nv << 2) + t; e < e1; e += 512) {
      unsigned d = (unsigned)dst[e];
      unsigned bk = d >> 5;
      int pos = atomicAdd(&lcur[bk], 1);
      P2g[pos] = (unsigned)src[e] | ((d & 31u) << 16);
    }

  } else {
    // ---------------- MFMA GEMM (h fp32 read + in-reg RNE cvt) -------------
    unsigned* ldegw = (unsigned*)lcnt;   // 64 u16-packed degrees
    const int gb = b - PG_PART;
    const int g = gb / PG_GEMM_PER;
    const int blk = gb % PG_GEMM_PER;
    const int row0 = blk * 128;
    unsigned short* __restrict__ xg = x + (size_t)g * N * NCOLS;

    if (t < 64) ldegw[t] = 0;
    __syncthreads();
    if (t < 256) {
      const unsigned* __restrict__ Pg = P8 + (size_t)g * NHCH * HW;
      const int widx = t >> 3;
      const int cg = t & 7;
      const int wcol = min((row0 >> 2) + widx, HW - 1);
      unsigned lo = 0, hi = 0;
      #pragma unroll
      for (int cc = 0; cc < 8; ++cc) {
        unsigned wv = Pg[(size_t)(cg * 8 + cc) * HW + wcol];
        lo += wv & 0x00FF00FFu;
        hi += (wv >> 8) & 0x00FF00FFu;
      }
      atomicAdd(&ldegw[2 * widx], lo);
      atomicAdd(&ldegw[2 * widx + 1], hi);
    }

    const int lane = t & 63;
    const int w = t >> 6;              // wave id: rows row0+16w .. +15
    const int quad = lane >> 4;
    const int n = lane & 15;

    int arow = min(row0 + w * 16 + n, N - 1);
    const float* hrowf = h + (size_t)arow * KDIM + quad * 8;
    bf16x8 a0 = ld_cvt8(hrowf);
    bf16x8 a1 = ld_cvt8(hrowf + 32);
    bf16x8 a2 = ld_cvt8(hrowf + 64);
    bf16x8 a3 = ld_cvt8(hrowf + 96);

    const uint4* wfp = (const uint4*)Wf + (size_t)g * 1024 + lane;

    f32x4 acc[4];
    #pragma unroll
    for (int c = 0; c < 4; ++c) acc[c] = (f32x4)(0.f);

    __syncthreads();   // ldegw ready

    #pragma unroll
    for (int c = 0; c < 4; ++c) {
      union { uint4 u; bf16x8 v; } b0, b1, b2, b3;
      b0.u = wfp[(size_t)(c * 4 + 0) * 64];
      b1.u = wfp[(size_t)(c * 4 + 1) * 64];
      b2.u = wfp[(size_t)(c * 4 + 2) * 64];
      b3.u = wfp[(size_t)(c * 4 + 3) * 64];
      acc[c] = __builtin_amdgcn_mfma_f32_16x16x32_bf16(a0, b0.v, acc[c], 0, 0, 0);
      acc[c] = __builtin_amdgcn_mfma_f32_16x16x32_bf16(a1, b1.v, acc[c], 0, 0, 0);
      acc[c] = __builtin_amdgcn_mfma_f32_16x16x32_bf16(a2, b2.v, acc[c], 0, 0, 0);
      acc[c] = __builtin_amdgcn_mfma_f32_16x16x32_bf16(a3, b3.v, acc[c], 0, 0, 0);
    }

    const int rbase = row0 + w * 16 + quad * 4;
    #pragma unroll
    for (int r = 0; r < 4; ++r) {
      int row = rbase + r;
      if (row < N) {
        int lr = row - row0;
        float dg = (float)((ldegw[2 * (lr >> 2) + (lr & 1)] >> (((lr >> 1) & 1) * 16)) & 0xFFFFu);
        float s = rsqrtf(fmaxf(dg, 1.0f));
        uint2 o;
        o.x = (unsigned)f2bf(acc[0][r] * s) | ((unsigned)f2bf(acc[1][r] * s) << 16);
        o.y = (unsigned)f2bf(acc[2][r] * s) | ((unsigned)f2bf(acc[3][r] * s) << 16);
        *(uint2*)(xg + (size_t)row * NCOLS + 4 * n) = o;
      }
    }
  }
}

// ---------------- SpMM: 32-node buckets, 2 parity-halves/node, shfl combine -
__global__ __launch_bounds__(512) void spmm_all_kernel(
    GArgs A, const unsigned* __restrict__ P2, const int* __restrict__ off,
    const unsigned short* __restrict__ x, float* __restrict__ out,
    int N, int Emax) {
  __shared__ unsigned eb[FCAP];            // staged edges src|ldst<<16
  __shared__ unsigned short srcs[FCAP];    // node-sorted src ids
  __shared__ int cnt[BUCKET];
  __shared__ int cur[BUCKET];
  __shared__ int rsx[BUCKET + 1];

  const int t = threadIdx.x;
  const int bk = blockIdx.x;
  const int dbase = bk * BUCKET;
  const int nd = min(BUCKET, N - dbase);
  const int grp = t >> 3;            // 0..63
  const int ni = grp >> 1;           // node 0..31
  const int half = grp & 1;          // parity half of the node's edge list
  const int qe = (t & 7) * 8;

  float tot[8];
  #pragma unroll
  for (int j = 0; j < 8; ++j) tot[j] = 0.f;

  for (int g = 0; g < 3; ++g) {
    const unsigned* __restrict__ P2g = P2 + (size_t)g * Emax;
    const unsigned short* __restrict__ xg = x + (size_t)g * N * NCOLS;

    __syncthreads();                       // previous-g reads complete
    if (t < BUCKET) cnt[t] = 0;
    __syncthreads();

    const int e0 = off[g * (NB5 + 1) + bk];
    const int ne = min(off[g * (NB5 + 1) + bk + 1] - e0, FCAP);
    for (int i = t; i < ne; i += 512) {
      unsigned e = P2g[e0 + i];
      eb[i] = e;
      atomicAdd(&cnt[e >> 16], 1);
    }
    __syncthreads();

    // wave-level exclusive scan of cnt[0..31] (lanes 0..31 of wave 0)
    if (t < BUCKET) {
      int v = cnt[t];
      int incl = v;
      #pragma unroll
      for (int o = 1; o < BUCKET; o <<= 1) {
        int u = __shfl_up(incl, o, 64);
        if (t >= o) incl += u;
      }
      rsx[t + 1] = incl;
      cur[t] = incl - v;
      if (t == 0) rsx[0] = 0;
    }
    __syncthreads();

    for (int i = t; i < ne; i += 512) {
      unsigned e = eb[i];
      int pos = atomicAdd(&cur[e >> 16], 1);
      srcs[pos] = (unsigned short)(e & 0xFFFFu);
    }
    __syncthreads();

    if (ni < nd) {
      const int ibase = rsx[ni];
      const int iend = rsx[ni + 1];
      const int deg = iend - ibase;
      float acc[8];
      #pragma unroll
      for (int j = 0; j < 8; ++j) acc[j] = 0.f;
      int i = ibase + half;              // this half's parity slice
      for (; i + 6 < iend; i += 8) {
        int sa = srcs[i + 0];
        int sb = srcs[i + 2];
        int sc = srcs[i + 4];
        int sdd = srcs[i + 6];
        uint4 ua = *(const uint4*)&xg[(size_t)sa * NCOLS + qe];
        uint4 ub = *(const uint4*)&xg[(size_t)sb * NCOLS + qe];
        uint4 uc = *(const uint4*)&xg[(size_t)sc * NCOLS + qe];
        uint4 ud = *(const uint4*)&xg[(size_t)sdd * NCOLS + qe];
        acc[0] += bflo(ua.x) + bflo(ub.x) + bflo(uc.x) + bflo(ud.x);
        acc[1] += bfhi(ua.x) + bfhi(ub.x) + bfhi(uc.x) + bfhi(ud.x);
        acc[2] += bflo(ua.y) + bflo(ub.y) + bflo(uc.y) + bflo(ud.y);
        acc[3] += bfhi(ua.y) + bfhi(ub.y) + bfhi(uc.y) + bfhi(ud.y);
        acc[4] += bflo(ua.z) + bflo(ub.z) + bflo(uc.z) + bflo(ud.z);
        acc[5] += bfhi(ua.z) + bfhi(ub.z) + bfhi(uc.z) + bfhi(ud.z);
        acc[6] += bflo(ua.w) + bflo(ub.w) + bflo(uc.w) + bflo(ud.w);
        acc[7] += bfhi(ua.w) + bfhi(ub.w) + bfhi(uc.w) + bfhi(ud.w);
      }
      for (; i < iend; i += 2) {
        int s = srcs[i];
        uint4 u = *(const uint4*)&xg[(size_t)s * NCOLS + qe];
        acc[0] += bflo(u.x); acc[1] += bfhi(u.x);
        acc[2] += bflo(u.y); acc[3] += bfhi(u.y);
        acc[4] += bflo(u.z); acc[5] += bfhi(u.z);
        acc[6] += bflo(u.w); acc[7] += bfhi(u.w);
      }
      // pair-combine: partner is t^8 (same wave) -- both get the full sum
      #pragma unroll
      for (int j = 0; j < 8; ++j) acc[j] += __shfl_xor(acc[j], 8, 64);
      float sc2 = rsqrtf(fmaxf((float)deg, 1.0f));
      const float* bg = A.b[g] + qe;
      #pragma unroll
      for (int j = 0; j < 8; ++j)
        tot[j] += fmaxf(fmaf(acc[j], sc2, bg[j]), 0.f) * (1.0f / 3.0f);
    }
  }

  if (ni < nd && half == 0) {
    float* op = &out[(size_t)(dbase + ni) * NCOLS + qe];
    *(float4*)&op[0] = make_float4(tot[0], tot[1], tot[2], tot[3]);
    *(float4*)&op[4] = make_float4(tot[4], tot[5], tot[6], tot[7]);
  }
}

extern "C" void kernel_launch(void* const* d_in, const int* in_sizes, int n_in,
                              void* d_out, int out_size, void* d_ws, size_t ws_size,
                              hipStream_t stream) {
  const float* h = (const float*)d_in[0];
  const int N = in_sizes[0] / KDIM;   // 50000
  float* out = (float*)d_out;

  GArgs A;
  int Emax = 0;
  for (int g = 0; g < 3; ++g) {
    A.src[g] = (const int*)  d_in[1 + g * 4];
    A.dst[g] = (const int*)  d_in[2 + g * 4];
    A.W[g]   = (const float*)d_in[3 + g * 4];
    A.b[g]   = (const float*)d_in[4 + g * 4];
    A.E[g]   = in_sizes[1 + g * 4];
    if (A.E[g] > Emax) Emax = A.E[g];
  }

  // ws: x 19.2 | P2 19.2 | P8 9.6 | Wf 48K | Pcnt 1.6 | tot/cursor/off ~56 KB
  char* w = (char*)d_ws;
  unsigned short* x = (unsigned short*)w;
  char* w2 = w + (size_t)3 * N * NCOLS * sizeof(unsigned short);
  unsigned* P2 = (unsigned*)w2;
  char* w3 = w2 + (size_t)3 * Emax * sizeof(unsigned);
  unsigned* P8 = (unsigned*)w3;
  char* w4 = w3 + (size_t)3 * NHCH * HW * sizeof(unsigned);
  unsigned short* Wf = (unsigned short*)w4;            // 3*16*64*8 u16 = 48 KB
  char* w5 = w4 + (size_t)3 * 16 * 64 * 8 * sizeof(unsigned short);
  int* Pcnt = (int*)w5;                                // [3*NPB][NB5] = 1.6 MB
  char* w6 = w5 + (size_t)3 * NPB * NB5 * sizeof(int);
  int* tot    = (int*)w6;                              // [3][1563]
  int* cursor = tot + 3 * NB5;                         // [3][1563]
  int* off    = cursor + 3 * NB5;                      // [3][1564]

  hipMemsetAsync(tot, 0, 2 * 3 * NB5 * sizeof(int), stream);
  prep_kernel<<<PREP_GRID, 256, 0, stream>>>(A, Wf, P8, tot, Pcnt);
  pg_kernel<<<PG_GRID, 512, 0, stream>>>(A, h, Wf, P8, tot, Pcnt, cursor, off, P2, x, N, Emax);
  spmm_all_kernel<<<NB5, 512, 0, stream>>>(A, P2, off, x, out, N, Emax);
}

// Round 10
// 249.785 us; speedup vs baseline: 1.0664x; 1.0664x over previous
//
// ============================================================================
// Round 23: 3 dispatches (prep, pg, spmm) -- memset + global cursor DELETED.
// prep count branch writes Pcnt only (no tot atomics). pg partition blocks
// derive tot[bin]=SUM_b Pcnt[b][bin] and mybase[bin]=SUM_{b<blk} Pcnt[b][bin]
// from Pcnt directly (85 coalesced L2-hot rows, ~1-2us), then LDS scan ->
// lcur = binoff + mybase. P2 layout now deterministic; no cursor atomics.
// spmm/bins REVERTED to known-good 782-bin / BUCKET=64 (spmm 73us measured).
// gemm = R20 h-direct version. All arithmetic identical -> absmax exactly
// 0.001953125.
//
// Measured R22: 266.4 (regression). spmm 71.2 @ Occ 47% (fabric-bound, not
// concurrency); pg VISIBLE: 71.3, WRITE 146MB (P2 cross-XCD false sharing at
// 1563 bins); prep < 71. Ledger implies ~40-60us of inter-dispatch overhead
// (~10us/launch) -- explains the R19-R21 work-deletion plateau.
//
// Predicted: spmm 73+-1 (FETCH ~148MB, conflicts ~1.12M), pg ~68-72, one
// dispatch+boundary deleted -> total ~242-250. Pre-commit: total >= 252 ->
// launch-overhead theory wrong too -> declare ROOFLINE on best config.
// ============================================================================
#include <hip/hip_runtime.h>

#define KDIM 128
#define NCOLS 64
// u8-packed src-degree histogram: one range, 50000 bins / 4 per word
#define NHCH 64
#define HW 12500
// fine buckets (partition + spmm granularity)
#define BUCKET 64
#define NB7 782
#define FCAP 2816
// partition blocks per graph
#define NPB 85
// prep task ranges
#define PREP_HIST (3 * NHCH)   // 192 hist blocks
#define PREP_CNT  (3 * NPB)    // 255 bucket-count blocks
#define PREP_WF   12           // wfrag blocks
#define PREP_GRID (PREP_HIST + PREP_CNT + PREP_WF)   // 459
// pg (partition + gemm fused): partition FIRST (long pole)
#define PG_PART (3 * NPB)            // 255
#define PG_GEMM_PER 391              // (50000+127)/128
#define PG_GEMM (3 * PG_GEMM_PER)    // 1173
#define PG_GRID (PG_PART + PG_GEMM)  // 1428

typedef __attribute__((ext_vector_type(8))) short bf16x8;
typedef __attribute__((ext_vector_type(4))) float f32x4;

struct GArgs {
  const int*   src[3];
  const int*   dst[3];
  const float* W[3];
  const float* b[3];
  int          E[3];
};

__device__ __forceinline__ unsigned short f2bf(float f) {
  unsigned u = __float_as_uint(f);
  u += 0x7FFFu + ((u >> 16) & 1u);   // RNE
  return (unsigned short)(u >> 16);
}
__device__ __forceinline__ float bflo(unsigned u) { return __uint_as_float(u << 16); }
__device__ __forceinline__ float bfhi(unsigned u) { return __uint_as_float(u & 0xFFFF0000u); }

// load 8 fp32 -> bf16x8 fragment (RNE, bit-identical to staged conversion)
__device__ __forceinline__ bf16x8 ld_cvt8(const float* __restrict__ p) {
  float4 f0 = *(const float4*)p;
  float4 f1 = *(const float4*)(p + 4);
  union { uint4 u; bf16x8 v; } cv;
  cv.u.x = (unsigned)f2bf(f0.x) | ((unsigned)f2bf(f0.y) << 16);
  cv.u.y = (unsigned)f2bf(f0.z) | ((unsigned)f2bf(f0.w) << 16);
  cv.u.z = (unsigned)f2bf(f1.x) | ((unsigned)f2bf(f1.y) << 16);
  cv.u.w = (unsigned)f2bf(f1.z) | ((unsigned)f2bf(f1.w) << 16);
  return cv.v;
}

// ---------------- fused front-end: hist | count(Pcnt only) | wfrag ----------
__global__ __launch_bounds__(256) void prep_kernel(
    GArgs A, unsigned short* __restrict__ Wf, unsigned* __restrict__ P8,
    int* __restrict__ Pcnt) {
  __shared__ unsigned sbuf[HW];   // 50 KB; hist uses all, count uses prefix
  const int b = blockIdx.x;
  const int t = threadIdx.x;

  if (b < PREP_HIST) {
    // -------- u8-packed src histogram, single pass over all 50000 bins -----
    const int g = b >> 6;
    const int chunk = b & 63;
    const int E = A.E[g];
    const int per_chunk = (((E + NHCH - 1) / NHCH) + 3) & ~3;
    const int* __restrict__ keys = A.src[g];
    for (int i = t; i < HW; i += 256) sbuf[i] = 0;
    __syncthreads();
    const int e0 = chunk * per_chunk;
    const int e1 = min(e0 + per_chunk, E);
    const int nn = max(e1 - e0, 0);
    const int nv = nn >> 2;
    const int4* k4p = (const int4*)&keys[e0];
    for (int v = t; v < nv; v += 256) {
      int4 k = k4p[v];
      atomicAdd(&sbuf[(unsigned)k.x >> 2], 1u << (((unsigned)k.x & 3u) * 8));
      atomicAdd(&sbuf[(unsigned)k.y >> 2], 1u << (((unsigned)k.y & 3u) * 8));
      atomicAdd(&sbuf[(unsigned)k.z >> 2], 1u << (((unsigned)k.z & 3u) * 8));
      atomicAdd(&sbuf[(unsigned)k.w >> 2], 1u << (((unsigned)k.w & 3u) * 8));
    }
    for (int e = e0 + (nv << 2) + t; e < e1; e += 256) {
      unsigned k = (unsigned)keys[e];
      atomicAdd(&sbuf[k >> 2], 1u << ((k & 3u) * 8));
    }
    __syncthreads();
    unsigned* __restrict__ dstp = P8 + (size_t)b * HW;   // b == g*64+chunk
    for (int i = t; i < HW; i += 256) dstp[i] = sbuf[i];

  } else if (b < PREP_HIST + PREP_CNT) {
    // -------- fine bucket (dst>>6) count; persist per-block counts ---------
    const int bb = b - PREP_HIST;
    const int g = bb / NPB;
    const int blk = bb % NPB;
    const int E = A.E[g];
    const int per_block = (((E + NPB - 1) / NPB) + 3) & ~3;
    const int* __restrict__ dst = A.dst[g];
    int* hcnt = (int*)sbuf;
    for (int i = t; i < NB7; i += 256) hcnt[i] = 0;
    __syncthreads();
    const int e0 = blk * per_block;
    const int e1 = min(e0 + per_block, E);
    const int nn = max(e1 - e0, 0);
    const int nv = nn >> 2;
    const int4* d4 = (const int4*)&dst[e0];
    for (int v = t; v < nv; v += 256) {
      int4 d = d4[v];
      atomicAdd(&hcnt[(unsigned)d.x >> 6], 1);
      atomicAdd(&hcnt[(unsigned)d.y >> 6], 1);
      atomicAdd(&hcnt[(unsigned)d.z >> 6], 1);
      atomicAdd(&hcnt[(unsigned)d.w >> 6], 1);
    }
    for (int e = e0 + (nv << 2) + t; e < e1; e += 256)
      atomicAdd(&hcnt[(unsigned)dst[e] >> 6], 1);
    __syncthreads();
    int* __restrict__ pc = Pcnt + (size_t)bb * NB7;
    for (int i = t; i < NB7; i += 256) pc[i] = hcnt[i];

  } else {
    // -------- W -> MFMA B-fragment layout, PERMUTED columns ----------------
    // B-frag (c, lane n) holds logical W column (4n + c): MFMA C/D at lane n,
    // acc[c][r] is logical col 4n+c -> contiguous 8B epilogue store.
    int tid = (b - PREP_HIST - PREP_CNT) * 256 + t;   // < 3072 always
    int lane = tid & 63;
    int frag = (tid >> 6) & 15;
    int g = tid >> 10;
    int c = frag >> 2, kk = frag & 3;
    int n = lane & 15, quad = lane >> 4;
    const float* W = A.W[g];
    unsigned short v[8];
    #pragma unroll
    for (int j = 0; j < 8; ++j) {
      int k = 32 * kk + quad * 8 + j;
      v[j] = f2bf(W[k * 64 + 4 * n + c]);
    }
    uint4 u;
    u.x = (unsigned)v[0] | ((unsigned)v[1] << 16);
    u.y = (unsigned)v[2] | ((unsigned)v[3] << 16);
    u.z = (unsigned)v[4] | ((unsigned)v[5] << 16);
    u.w = (unsigned)v[6] | ((unsigned)v[7] << 16);
    ((uint4*)Wf)[tid] = u;
  }
}

// ---------------- fused partition + MFMA GEMM (no cursor, no tot) -----------
__global__ __launch_bounds__(512) void pg_kernel(
    GArgs A, const float* __restrict__ h,
    const unsigned short* __restrict__ Wf, const unsigned* __restrict__ P8,
    const int* __restrict__ Pcnt, int* __restrict__ off,
    unsigned* __restrict__ P2, unsigned short* __restrict__ x,
    int N, int Emax) {
  __shared__ int lcnt[NB7];   // tot[bin] (sum over all 85 blocks)
  __shared__ int lcur[NB7];   // this block's base within bin, then cursor
  __shared__ int sd[512];
  const int b = blockIdx.x;
  const int t = threadIdx.x;

  if (b < PG_PART) {
    // ---------------- fine partition: reduce Pcnt, scan, scatter -----------
    const int g = b / NPB;
    const int blk = b % NPB;
    const int E = A.E[g];
    const int per_block = (((E + NPB - 1) / NPB) + 3) & ~3;
    const int* __restrict__ src = A.src[g];
    const int* __restrict__ dst = A.dst[g];
    unsigned* __restrict__ P2g = P2 + (size_t)g * Emax;

    // tot[bin] and mybase[bin] from Pcnt (85 coalesced rows, L2-hot)
    const int* __restrict__ pcg = Pcnt + (size_t)g * NPB * NB7;
    for (int idx = t; idx < NB7; idx += 512) {
      int sum = 0, base = 0;
      for (int bb = 0; bb < NPB; ++bb) {
        int c = pcg[(size_t)bb * NB7 + idx];
        sum += c;
        if (bb < blk) base += c;
      }
      lcnt[idx] = sum;
      lcur[idx] = base;
    }
    __syncthreads();

    // exclusive scan of tot over 782 bins; lcur += binoff
    int base = 0;
    for (int c0 = 0; c0 < NB7; c0 += 512) {
      int idx = c0 + t;
      int v = (idx < NB7) ? lcnt[idx] : 0;
      sd[t] = v;
      __syncthreads();
      for (int o = 1; o < 512; o <<= 1) {
        int add = (t >= o) ? sd[t - o] : 0;
        __syncthreads();
        sd[t] += add;
        __syncthreads();
      }
      int excl = base + sd[t] - v;
      if (idx < NB7) {
        lcur[idx] += excl;
        if (blk == 0) off[g * (NB7 + 1) + idx] = excl;
      }
      base += sd[511];
      __syncthreads();
    }
    if (blk == 0 && t == 0) off[g * (NB7 + 1) + NB7] = base;
    __syncthreads();

    const int e0 = blk * per_block;
    const int e1 = min(e0 + per_block, E);
    const int nn = max(e1 - e0, 0);
    const int nv = nn >> 2;
    const int4* d4 = (const int4*)&dst[e0];
    const int4* s4 = (const int4*)&src[e0];
    for (int v = t; v < nv; v += 512) {
      int4 d = d4[v];
      int4 s = s4[v];
      unsigned bk; int pos;
      bk = (unsigned)d.x >> 6; pos = atomicAdd(&lcur[bk], 1);
      P2g[pos] = (unsigned)s.x | (((unsigned)d.x & 63u) << 16);
      bk = (unsigned)d.y >> 6; pos = atomicAdd(&lcur[bk], 1);
      P2g[pos] = (unsigned)s.y | (((unsigned)d.y & 63u) << 16);
      bk = (unsigned)d.z >> 6; pos = atomicAdd(&lcur[bk], 1);
      P2g[pos] = (unsigned)s.z | (((unsigned)d.z & 63u) << 16);
      bk = (unsigned)d.w >> 6; pos = atomicAdd(&lcur[bk], 1);
      P2g[pos] = (unsigned)s.w | (((unsigned)d.w & 63u) << 16);
    }
    for (int e = e0 + (nv << 2) + t; e < e1; e += 512) {
      unsigned d = (unsigned)dst[e];
      unsigned bk = d >> 6;
      int pos = atomicAdd(&lcur[bk], 1);
      P2g[pos] = (unsigned)src[e] | ((d & 63u) << 16);
    }

  } else {
    // ---------------- MFMA GEMM (h fp32 read + in-reg RNE cvt) -------------
    unsigned* ldegw = (unsigned*)lcnt;   // 64 u16-packed degrees
    const int gb = b - PG_PART;
    const int g = gb / PG_GEMM_PER;
    const int blk = gb % PG_GEMM_PER;
    const int row0 = blk * 128;
    unsigned short* __restrict__ xg = x + (size_t)g * N * NCOLS;

    if (t < 64) ldegw[t] = 0;
    __syncthreads();
    if (t < 256) {
      const unsigned* __restrict__ Pg = P8 + (size_t)g * NHCH * HW;
      const int widx = t >> 3;
      const int cg = t & 7;
      const int wcol = min((row0 >> 2) + widx, HW - 1);
      unsigned lo = 0, hi = 0;
      #pragma unroll
      for (int cc = 0; cc < 8; ++cc) {
        unsigned wv = Pg[(size_t)(cg * 8 + cc) * HW + wcol];
        lo += wv & 0x00FF00FFu;
        hi += (wv >> 8) & 0x00FF00FFu;
      }
      atomicAdd(&ldegw[2 * widx], lo);
      atomicAdd(&ldegw[2 * widx + 1], hi);
    }

    const int lane = t & 63;
    const int w = t >> 6;              // wave id: rows row0+16w .. +15
    const int quad = lane >> 4;
    const int n = lane & 15;

    int arow = min(row0 + w * 16 + n, N - 1);
    const float* hrowf = h + (size_t)arow * KDIM + quad * 8;
    bf16x8 a0 = ld_cvt8(hrowf);
    bf16x8 a1 = ld_cvt8(hrowf + 32);
    bf16x8 a2 = ld_cvt8(hrowf + 64);
    bf16x8 a3 = ld_cvt8(hrowf + 96);

    const uint4* wfp = (const uint4*)Wf + (size_t)g * 1024 + lane;

    f32x4 acc[4];
    #pragma unroll
    for (int c = 0; c < 4; ++c) acc[c] = (f32x4)(0.f);

    __syncthreads();   // ldegw ready

    #pragma unroll
    for (int c = 0; c < 4; ++c) {
      union { uint4 u; bf16x8 v; } b0, b1, b2, b3;
      b0.u = wfp[(size_t)(c * 4 + 0) * 64];
      b1.u = wfp[(size_t)(c * 4 + 1) * 64];
      b2.u = wfp[(size_t)(c * 4 + 2) * 64];
      b3.u = wfp[(size_t)(c * 4 + 3) * 64];
      acc[c] = __builtin_amdgcn_mfma_f32_16x16x32_bf16(a0, b0.v, acc[c], 0, 0, 0);
      acc[c] = __builtin_amdgcn_mfma_f32_16x16x32_bf16(a1, b1.v, acc[c], 0, 0, 0);
      acc[c] = __builtin_amdgcn_mfma_f32_16x16x32_bf16(a2, b2.v, acc[c], 0, 0, 0);
      acc[c] = __builtin_amdgcn_mfma_f32_16x16x32_bf16(a3, b3.v, acc[c], 0, 0, 0);
    }

    const int rbase = row0 + w * 16 + quad * 4;
    #pragma unroll
    for (int r = 0; r < 4; ++r) {
      int row = rbase + r;
      if (row < N) {
        int lr = row - row0;
        float dg = (float)((ldegw[2 * (lr >> 2) + (lr & 1)] >> (((lr >> 1) & 1) * 16)) & 0xFFFFu);
        float s = rsqrtf(fmaxf(dg, 1.0f));
        uint2 o;
        o.x = (unsigned)f2bf(acc[0][r] * s) | ((unsigned)f2bf(acc[1][r] * s) << 16);
        o.y = (unsigned)f2bf(acc[2][r] * s) | ((unsigned)f2bf(acc[3][r] * s) << 16);
        *(uint2*)(xg + (size_t)row * NCOLS + 4 * n) = o;
      }
    }
  }
}

// ---------------- SpMM: in-LDS counting sort + register accumulation --------
__global__ __launch_bounds__(512) void spmm_all_kernel(
    GArgs A, const unsigned* __restrict__ P2, const int* __restrict__ off,
    const unsigned short* __restrict__ x, float* __restrict__ out,
    int N, int Emax) {
  __shared__ unsigned eb[FCAP];            // staged edges src|ldst<<16
  __shared__ unsigned short srcs[FCAP];    // node-sorted src ids
  __shared__ int cnt[BUCKET];
  __shared__ int cur[BUCKET];
  __shared__ int rsx[BUCKET + 1];

  const int t = threadIdx.x;
  const int bk = blockIdx.x;
  const int dbase = bk * BUCKET;
  const int nd = min(BUCKET, N - dbase);
  const int grp = t >> 3;
  const int qe = (t & 7) * 8;

  float tot[8];
  #pragma unroll
  for (int j = 0; j < 8; ++j) tot[j] = 0.f;

  for (int g = 0; g < 3; ++g) {
    const unsigned* __restrict__ P2g = P2 + (size_t)g * Emax;
    const unsigned short* __restrict__ xg = x + (size_t)g * N * NCOLS;

    __syncthreads();                       // previous-g reads complete
    if (t < BUCKET) cnt[t] = 0;
    __syncthreads();

    const int e0 = off[g * (NB7 + 1) + bk];
    const int ne = min(off[g * (NB7 + 1) + bk + 1] - e0, FCAP);
    for (int i = t; i < ne; i += 512) {
      unsigned e = P2g[e0 + i];
      eb[i] = e;
      atomicAdd(&cnt[e >> 16], 1);
    }
    __syncthreads();

    // wave-level exclusive scan of cnt[0..63] (lanes of wave 0, no syncs)
    if (t < BUCKET) {
      int v = cnt[t];
      int incl = v;
      #pragma unroll
      for (int o = 1; o < 64; o <<= 1) {
        int u = __shfl_up(incl, o, 64);
        if (t >= o) incl += u;
      }
      rsx[t + 1] = incl;
      cur[t] = incl - v;
      if (t == 0) rsx[0] = 0;
    }
    __syncthreads();

    for (int i = t; i < ne; i += 512) {
      unsigned e = eb[i];
      int pos = atomicAdd(&cur[e >> 16], 1);
      srcs[pos] = (unsigned short)(e & 0xFFFFu);
    }
    __syncthreads();

    if (grp < nd) {
      int i = rsx[grp];
      const int iend = rsx[grp + 1];
      const int deg = iend - i;
      float acc[8];
      #pragma unroll
      for (int j = 0; j < 8; ++j) acc[j] = 0.f;
      for (; i + 3 < iend; i += 4) {
        int sa = srcs[i + 0];
        int sb = srcs[i + 1];
        int sc = srcs[i + 2];
        int sdd = srcs[i + 3];
        uint4 ua = *(const uint4*)&xg[(size_t)sa * NCOLS + qe];
        uint4 ub = *(const uint4*)&xg[(size_t)sb * NCOLS + qe];
        uint4 uc = *(const uint4*)&xg[(size_t)sc * NCOLS + qe];
        uint4 ud = *(const uint4*)&xg[(size_t)sdd * NCOLS + qe];
        acc[0] += bflo(ua.x) + bflo(ub.x) + bflo(uc.x) + bflo(ud.x);
        acc[1] += bfhi(ua.x) + bfhi(ub.x) + bfhi(uc.x) + bfhi(ud.x);
        acc[2] += bflo(ua.y) + bflo(ub.y) + bflo(uc.y) + bflo(ud.y);
        acc[3] += bfhi(ua.y) + bfhi(ub.y) + bfhi(uc.y) + bfhi(ud.y);
        acc[4] += bflo(ua.z) + bflo(ub.z) + bflo(uc.z) + bflo(ud.z);
        acc[5] += bfhi(ua.z) + bfhi(ub.z) + bfhi(uc.z) + bfhi(ud.z);
        acc[6] += bflo(ua.w) + bflo(ub.w) + bflo(uc.w) + bflo(ud.w);
        acc[7] += bfhi(ua.w) + bfhi(ub.w) + bfhi(uc.w) + bfhi(ud.w);
      }
      for (; i < iend; ++i) {
        int s = srcs[i];
        uint4 u = *(const uint4*)&xg[(size_t)s * NCOLS + qe];
        acc[0] += bflo(u.x); acc[1] += bfhi(u.x);
        acc[2] += bflo(u.y); acc[3] += bfhi(u.y);
        acc[4] += bflo(u.z); acc[5] += bfhi(u.z);
        acc[6] += bflo(u.w); acc[7] += bfhi(u.w);
      }
      float sc2 = rsqrtf(fmaxf((float)deg, 1.0f));
      const float* bg = A.b[g] + qe;
      #pragma unroll
      for (int j = 0; j < 8; ++j)
        tot[j] += fmaxf(fmaf(acc[j], sc2, bg[j]), 0.f) * (1.0f / 3.0f);
    }
  }

  if (grp < nd) {
    float* op = &out[(size_t)(dbase + grp) * NCOLS + qe];
    *(float4*)&op[0] = make_float4(tot[0], tot[1], tot[2], tot[3]);
    *(float4*)&op[4] = make_float4(tot[4], tot[5], tot[6], tot[7]);
  }
}

extern "C" void kernel_launch(void* const* d_in, const int* in_sizes, int n_in,
                              void* d_out, int out_size, void* d_ws, size_t ws_size,
                              hipStream_t stream) {
  const float* h = (const float*)d_in[0];
  const int N = in_sizes[0] / KDIM;   // 50000
  float* out = (float*)d_out;

  GArgs A;
  int Emax = 0;
  for (int g = 0; g < 3; ++g) {
    A.src[g] = (const int*)  d_in[1 + g * 4];
    A.dst[g] = (const int*)  d_in[2 + g * 4];
    A.W[g]   = (const float*)d_in[3 + g * 4];
    A.b[g]   = (const float*)d_in[4 + g * 4];
    A.E[g]   = in_sizes[1 + g * 4];
    if (A.E[g] > Emax) Emax = A.E[g];
  }

  // ws: x 19.2 | P2 19.2 | P8 9.6 | Wf 48K | Pcnt 0.8 | off ~9.4 KB
  char* w = (char*)d_ws;
  unsigned short* x = (unsigned short*)w;
  char* w2 = w + (size_t)3 * N * NCOLS * sizeof(unsigned short);
  unsigned* P2 = (unsigned*)w2;
  char* w3 = w2 + (size_t)3 * Emax * sizeof(unsigned);
  unsigned* P8 = (unsigned*)w3;
  char* w4 = w3 + (size_t)3 * NHCH * HW * sizeof(unsigned);
  unsigned short* Wf = (unsigned short*)w4;            // 3*16*64*8 u16 = 48 KB
  char* w5 = w4 + (size_t)3 * 16 * 64 * 8 * sizeof(unsigned short);
  int* Pcnt = (int*)w5;                                // [3*NPB][NB7] = 797 KB
  char* w6 = w5 + (size_t)3 * NPB * NB7 * sizeof(int);
  int* off = (int*)w6;                                 // [3][783]

  prep_kernel<<<PREP_GRID, 256, 0, stream>>>(A, Wf, P8, Pcnt);
  pg_kernel<<<PG_GRID, 512, 0, stream>>>(A, h, Wf, P8, Pcnt, off, P2, x, N, Emax);
  spmm_all_kernel<<<NB7, 512, 0, stream>>>(A, P2, off, x, out, N, Emax);
}